// Round 12
// baseline (458.718 us; speedup 1.0000x reference)
//
#include <hip/hip_runtime.h>
#include <hip/hip_fp16.h>

typedef unsigned long long u64;

#define C2X 2.8853900817779268f   // 2*log2(e)
#define LOG2E 1.4426950408889634f

// ---------------- workspace layout (bytes) ----------------
#define WYS_OFF   0u          // half [32][256][256]  WY (prescaled C2X)
#define PR_OFF    4194304u    // half [32][256][256]  P_r = prem @ w_r
#define PREMH_OFF 8388608u    // half [32][256][256]  premise fp16
#define HWH_OFF   12582912u   // f32  [128][32][256]  (h@w_h)*C2X
#define WTH_OFF   16777216u   // half [256][256]      w_t
#define WTR_OFF   16908288u   // half [256][256]      W_tr = w_t @ w_r
#define ZP_OFF    17039360u   // u64 [2][32][8][256]  tagged z-partials (1MB)
#define RCH_OFF   18087936u   // u64 [2][32][256]     tagged r-chunks (128KB)
#define MEMSET_SZ 1179648u

// ---------------- LDS layout (bytes) ----------------
// Transposed mats [32 d][256 l] half, row 512B, granule-swizzled ^((d&7)<<4)
#define PRT_OFF    0u        // P_r^T
#define WTRT_OFF   16384u    // W_tr^T
#define PREMT_OFF  32768u    // prem^T
#define WTT_OFF    49152u    // w_t^T
#define WYC_OFF    65536u    // [256 l][32 d] half, granule-swizzled ^((l&7)<<4)
#define HWHC_OFF   81920u    // [128][32] f32
#define SCH_OFF    98304u    // 32 f32
#define WACH_OFF   98432u    // 32 f32 (prescaled -2*LOG2E)
#define RED_OFF    98560u    // [2][4] f32 (+pad to 64)
#define ALB_OFF    98624u    // [2][264] f32 e (unnormalized), parity dbuf, padded stride
#define RBB_OFF    100736u   // [2][264] f32 r, parity dbuf, padded stride
#define LDS_TOTAL  102848u   // >80KB => 1 block/CU => all 256 co-resident

// ---------------- prep: everything in ONE launch (proven R7) ----------------
__global__ __launch_bounds__(256) void prep_all(const float* __restrict__ x,
                                                const float* __restrict__ wy,
                                                const float* __restrict__ wh,
                                                const float* __restrict__ wr,
                                                const float* __restrict__ wt,
                                                __half* __restrict__ wys,
                                                __half* __restrict__ prh,
                                                float* __restrict__ hwh,
                                                __half* __restrict__ wtrh,
                                                __half* __restrict__ premh,
                                                __half* __restrict__ wth) {
    const int blk = blockIdx.x;
    if (blk >= 1568) {
        int i = (blk - 1568) * 256 + threadIdx.x;   // quad index
        float4 v; __half* dst; int e;
        if (i < 524288) {
            e = i * 4; int b = e >> 16;
            v = *(const float4*)(x + (size_t)e + (size_t)b * 32768);
            dst = premh + e;
        } else if (i < 540672) {
            e = (i - 524288) * 4;
            v = *(const float4*)(wt + e);
            dst = wth + e;
        } else return;
        __half h[4] = {__float2half(v.x),__float2half(v.y),__float2half(v.z),__float2half(v.w)};
        *(uint2*)dst = *(const uint2*)h;
        return;
    }
    __shared__ float At[8][256];
    const int d = threadIdx.x;
    int mode, row0;
    if (blk < 1024)      { mode = 0; row0 = blk * 8; }
    else if (blk < 1536) { mode = 1; row0 = (blk - 1024) * 8; }
    else                 { mode = 2; row0 = (blk - 1536) * 8; }
    for (int rr = 0; rr < 8; ++rr) {
        int r = row0 + rr;
        const float* src;
        if (mode == 0)      { int b = r >> 8, l = r & 255; src = x + (size_t)(b * 384 + l) * 256; }
        else if (mode == 1) { int tt = r >> 5, bb = r & 31; src = x + (size_t)(bb * 384 + 256 + tt) * 256; }
        else                { src = wt + (size_t)r * 256; }
        At[rr][d] = src[d];
    }
    __syncthreads();
    if (mode == 0) {
        float accy[8] = {0,0,0,0,0,0,0,0}, accr[8] = {0,0,0,0,0,0,0,0};
        for (int k = 0; k < 256; k += 2) {
            float y0 = wy[(size_t)k * 256 + d], y1 = wy[(size_t)(k + 1) * 256 + d];
            float r0 = wr[(size_t)k * 256 + d], r1 = wr[(size_t)(k + 1) * 256 + d];
#pragma unroll
            for (int rr = 0; rr < 8; ++rr) {
                float2 a = *(const float2*)&At[rr][k];
                accy[rr] = fmaf(a.x, y0, accy[rr]); accy[rr] = fmaf(a.y, y1, accy[rr]);
                accr[rr] = fmaf(a.x, r0, accr[rr]); accr[rr] = fmaf(a.y, r1, accr[rr]);
            }
        }
        for (int rr = 0; rr < 8; ++rr) {
            int r = row0 + rr;
            wys[(size_t)r * 256 + d] = __float2half(accy[rr] * C2X);
            prh[(size_t)r * 256 + d] = __float2half(accr[rr]);
        }
    } else {
        const float* w = (mode == 1) ? wh : wr;
        float acc[8] = {0,0,0,0,0,0,0,0};
        for (int k = 0; k < 256; k += 4) {
            float w0 = w[(size_t)k * 256 + d], w1 = w[(size_t)(k+1) * 256 + d];
            float w2 = w[(size_t)(k+2) * 256 + d], w3 = w[(size_t)(k+3) * 256 + d];
#pragma unroll
            for (int rr = 0; rr < 8; ++rr) {
                float4 a = *(const float4*)&At[rr][k];
                float t0 = fmaf(a.x, w0, acc[rr]);
                t0 = fmaf(a.y, w1, t0);
                t0 = fmaf(a.z, w2, t0);
                acc[rr] = fmaf(a.w, w3, t0);
            }
        }
        for (int rr = 0; rr < 8; ++rr) {
            int r = row0 + rr;
            if (mode == 1) hwh[(size_t)r * 256 + d] = acc[rr] * C2X;
            else           wtrh[(size_t)r * 256 + d] = __float2half(acc[rr]);
        }
    }
}

// ---------------- agent-scope helpers ----------------
__device__ __forceinline__ u64 agent_load64(const u64* p) {
    return __hip_atomic_load(p, __ATOMIC_RELAXED, __HIP_MEMORY_SCOPE_AGENT);
}
__device__ __forceinline__ void agent_store64(u64* p, u64 v) {
    __hip_atomic_store(p, v, __ATOMIC_RELAXED, __HIP_MEMORY_SCOPE_AGENT);
}

// ---------------- main: 2-barrier step, wave-split A-phase, transposed mats ----------------
__global__ __launch_bounds__(512, 1) void wbw_main(
    const __half* __restrict__ wys, const __half* __restrict__ prh,
    const __half* __restrict__ premh, const __half* __restrict__ wth,
    const __half* __restrict__ wtrh, const float* __restrict__ hwh,
    const float* __restrict__ walpha, float* __restrict__ out,
    u64* __restrict__ zp, u64* __restrict__ rch)
{
    extern __shared__ char lds[];
    const int tid = threadIdx.x;
    const int b = blockIdx.x >> 3, j = blockIdx.x & 7;

    float* hwhc  = (float*)(lds + HWHC_OFF);
    float* s_ch  = (float*)(lds + SCH_OFF);
    float* wa_ch = (float*)(lds + WACH_OFF);
    float* redb  = (float*)(lds + RED_OFF);
    float* alb   = (float*)(lds + ALB_OFF);    // [2][264]
    float* rbb   = (float*)(lds + RBB_OFF);    // [2][264]

    // ---- stage 4 transposed+swizzled mats via b16 scatter ----
    {
        const __half* srcs[4] = { prh + (size_t)b * 65536, wtrh,
                                  premh + (size_t)b * 65536, wth };
#pragma unroll
        for (int m = 0; m < 4; ++m) {
            const uint4* s = (const uint4*)srcs[m];
            char* base = lds + (unsigned)m * 16384u;
            for (int it = 0; it < 2; ++it) {
                int idx = it * 512 + tid;       // 1024 uint4 per mat chunk
                int l = idx >> 2, dq = idx & 3;
                uint4 v = s[l * 32 + j * 4 + dq];
                const __half* hp = (const __half*)&v;
#pragma unroll
                for (int k = 0; k < 8; ++k) {
                    int d = dq * 8 + k;         // d&7 == k
                    *(__half*)(base + (unsigned)d * 512u +
                               (((unsigned)l * 2u) ^ ((unsigned)k << 4))) = hp[k];
                }
            }
        }
    }
    // ---- stage WY chunk [256 l][32 d], granule-swizzled ----
    {
        const uint4* s = (const uint4*)(wys + (size_t)b * 65536);
        for (int it = 0; it < 2; ++it) {
            int idx = it * 512 + tid;
            int l = idx >> 2, c = idx & 3;
            uint4 v = s[l * 32 + j * 4 + c];
            *(uint4*)(lds + WYC_OFF +
                      (((unsigned)(l * 64 + c * 16)) ^ (((unsigned)l & 7u) << 4))) = v;
        }
    }
    // ---- stage hwh chunk [128][32] f32 ----
    for (int it = 0; it < 8; ++it) {
        int idx = it * 512 + tid;
        int tt = idx >> 5, dd = idx & 31;
        hwhc[idx] = hwh[((size_t)tt * 32 + b) * 256 + j * 32 + dd];
    }
    if (tid < 32)  wa_ch[tid] = walpha[j * 32 + tid] * (-2.0f * LOG2E);
    if (tid < 256) { alb[tid] = 0.f; alb[264 + tid] = 0.f;
                     rbb[tid] = 0.f; rbb[264 + tid] = 0.f; }
    if (tid < 8)   redb[tid] = (tid == 0 || tid == 4) ? 1.f : 0.f;
    __syncthreads();

    for (int t = 0; t <= 128; ++t) {
        const int par = t & 1, q = par ^ 1;
        const float* e1 = alb + q * 264;           // e_{t-1}
        const float* rq = rbb + q * 264;           // r_{t-2}

        // ---- A-phase: waves0-3 s-GEMV->s_ch ; waves4-7 r-GEMV->publish ----
        {
            const int grp = tid >> 8;              // 0: s-side, 1: r-side
            const int k   = tid & 7;               // d&7
            const int lg  = (tid >> 3) & 7;
            const int d   = ((tid >> 6) & 3) * 8 + k;
            const int l0  = lg * 32;
            if (grp == 0 ? (t < 128) : true) {
                const char* mA = lds + (grp ? PREMT_OFF : PRT_OFF) + (unsigned)d * 512u;
                const char* mB = lds + (grp ? WTT_OFF : WTRT_OFF) + (unsigned)d * 512u;
                float ae = 0.f, ar = 0.f;
#pragma unroll
                for (int g = 0; g < 4; ++g) {
                    unsigned off = ((unsigned)(l0 * 2 + g * 16)) ^ ((unsigned)k << 4);
                    uint4 va = *(const uint4*)(mA + off);
                    uint4 vb = *(const uint4*)(mB + off);
                    const float4 e0 = *(const float4*)&e1[l0 + g * 8];
                    const float4 e4 = *(const float4*)&e1[l0 + g * 8 + 4];
                    const float4 r0 = *(const float4*)&rq[l0 + g * 8];
                    const float4 r4 = *(const float4*)&rq[l0 + g * 8 + 4];
                    const __half2* ha = (const __half2*)&va;
                    const __half2* hb = (const __half2*)&vb;
                    float2 f;
                    f = __half22float2(ha[0]); ae = fmaf(e0.x, f.x, ae); ae = fmaf(e0.y, f.y, ae);
                    f = __half22float2(ha[1]); ae = fmaf(e0.z, f.x, ae); ae = fmaf(e0.w, f.y, ae);
                    f = __half22float2(ha[2]); ae = fmaf(e4.x, f.x, ae); ae = fmaf(e4.y, f.y, ae);
                    f = __half22float2(ha[3]); ae = fmaf(e4.z, f.x, ae); ae = fmaf(e4.w, f.y, ae);
                    f = __half22float2(hb[0]); ar = fmaf(r0.x, f.x, ar); ar = fmaf(r0.y, f.y, ar);
                    f = __half22float2(hb[1]); ar = fmaf(r0.z, f.x, ar); ar = fmaf(r0.w, f.y, ar);
                    f = __half22float2(hb[2]); ar = fmaf(r4.x, f.x, ar); ar = fmaf(r4.y, f.y, ar);
                    f = __half22float2(hb[3]); ar = fmaf(r4.z, f.x, ar); ar = fmaf(r4.w, f.y, ar);
                }
                ae += __shfl_xor(ae, 8, 64);  ae += __shfl_xor(ae, 16, 64); ae += __shfl_xor(ae, 32, 64);
                ar += __shfl_xor(ar, 8, 64);  ar += __shfl_xor(ar, 16, 64); ar += __shfl_xor(ar, 32, 64);
                if (lg == 0) {
                    const float* rd = redb + q * 4;
                    float rD = __builtin_amdgcn_rcpf(rd[0] + rd[1] + rd[2] + rd[3]);
                    float v = fmaf(ae, rD, ar);
                    if (grp == 0) {
                        s_ch[d] = fmaf(v, C2X, hwhc[t * 32 + d]);
                    } else {
                        if (t >= 1) out[((size_t)b * 128 + (t - 1)) * 256 + j * 32 + d] = v;
                        rbb[par * 264 + j * 32 + d] = v;       // own-chunk LDS shortcut
                        if (t < 128) {
                            u64 pk = ((u64)(unsigned)t << 32) | (u64)__float_as_uint(v);
                            agent_store64(&rch[(size_t)(par * 32 + b) * 256 + j * 32 + d], pk);
                        }
                    }
                }
            }
        }
        __syncthreads();
        if (t == 128) break;

        // ---- C: sigma + tagged z publish (all 512 threads) ----
        {
            const int l = tid >> 1, c0 = (tid & 1) * 2, dh = (tid & 1) << 4;
            const unsigned key = ((unsigned)l & 7u) << 4;
            uint4 W0 = *(const uint4*)(lds + WYC_OFF + (((unsigned)(l * 64 + c0 * 16)) ^ key));
            uint4 W1 = *(const uint4*)(lds + WYC_OFF + (((unsigned)(l * 64 + c0 * 16 + 16)) ^ key));
            const float4 s0 = *(const float4*)&s_ch[dh];
            const float4 s1 = *(const float4*)&s_ch[dh + 4];
            const float4 s2 = *(const float4*)&s_ch[dh + 8];
            const float4 s3 = *(const float4*)&s_ch[dh + 12];
            const float4 w0 = *(const float4*)&wa_ch[dh];
            const float4 w1 = *(const float4*)&wa_ch[dh + 4];
            const float4 w2 = *(const float4*)&wa_ch[dh + 8];
            const float4 w3 = *(const float4*)&wa_ch[dh + 12];
            const __half2* h0 = (const __half2*)&W0;
            const __half2* h1 = (const __half2*)&W1;
            float acc = 0.f;
            float2 f;
#define SIG(hh, sv, wv) { float arg = f.x + sv.x; acc = fmaf(wv.x, __builtin_amdgcn_rcpf(__builtin_amdgcn_exp2f(arg) + 1.f), acc); \
                          arg = f.y + sv.y;      acc = fmaf(wv.y, __builtin_amdgcn_rcpf(__builtin_amdgcn_exp2f(arg) + 1.f), acc); }
            f = __half22float2(h0[0]); { float arg = f.x + s0.x; acc = fmaf(w0.x, __builtin_amdgcn_rcpf(__builtin_amdgcn_exp2f(arg) + 1.f), acc);
                                         arg = f.y + s0.y;       acc = fmaf(w0.y, __builtin_amdgcn_rcpf(__builtin_amdgcn_exp2f(arg) + 1.f), acc); }
            f = __half22float2(h0[1]); { float arg = f.x + s0.z; acc = fmaf(w0.z, __builtin_amdgcn_rcpf(__builtin_amdgcn_exp2f(arg) + 1.f), acc);
                                         arg = f.y + s0.w;       acc = fmaf(w0.w, __builtin_amdgcn_rcpf(__builtin_amdgcn_exp2f(arg) + 1.f), acc); }
            f = __half22float2(h0[2]); { float arg = f.x + s1.x; acc = fmaf(w1.x, __builtin_amdgcn_rcpf(__builtin_amdgcn_exp2f(arg) + 1.f), acc);
                                         arg = f.y + s1.y;       acc = fmaf(w1.y, __builtin_amdgcn_rcpf(__builtin_amdgcn_exp2f(arg) + 1.f), acc); }
            f = __half22float2(h0[3]); { float arg = f.x + s1.z; acc = fmaf(w1.z, __builtin_amdgcn_rcpf(__builtin_amdgcn_exp2f(arg) + 1.f), acc);
                                         arg = f.y + s1.w;       acc = fmaf(w1.w, __builtin_amdgcn_rcpf(__builtin_amdgcn_exp2f(arg) + 1.f), acc); }
            f = __half22float2(h1[0]); { float arg = f.x + s2.x; acc = fmaf(w2.x, __builtin_amdgcn_rcpf(__builtin_amdgcn_exp2f(arg) + 1.f), acc);
                                         arg = f.y + s2.y;       acc = fmaf(w2.y, __builtin_amdgcn_rcpf(__builtin_amdgcn_exp2f(arg) + 1.f), acc); }
            f = __half22float2(h1[1]); { float arg = f.x + s2.z; acc = fmaf(w2.z, __builtin_amdgcn_rcpf(__builtin_amdgcn_exp2f(arg) + 1.f), acc);
                                         arg = f.y + s2.w;       acc = fmaf(w2.w, __builtin_amdgcn_rcpf(__builtin_amdgcn_exp2f(arg) + 1.f), acc); }
            f = __half22float2(h1[2]); { float arg = f.x + s3.x; acc = fmaf(w3.x, __builtin_amdgcn_rcpf(__builtin_amdgcn_exp2f(arg) + 1.f), acc);
                                         arg = f.y + s3.y;       acc = fmaf(w3.y, __builtin_amdgcn_rcpf(__builtin_amdgcn_exp2f(arg) + 1.f), acc); }
            f = __half22float2(h1[3]); { float arg = f.x + s3.z; acc = fmaf(w3.z, __builtin_amdgcn_rcpf(__builtin_amdgcn_exp2f(arg) + 1.f), acc);
                                         arg = f.y + s3.w;       acc = fmaf(w3.w, __builtin_amdgcn_rcpf(__builtin_amdgcn_exp2f(arg) + 1.f), acc); }
#undef SIG
            acc += __shfl_xor(acc, 1, 64);
            if ((tid & 1) == 0) {
                u64 pk = ((u64)(unsigned)(t + 1) << 32) | (u64)__float_as_uint(acc);
                agent_store64(&zp[(size_t)((par * 32 + b) * 8 + j) * 256 + l], pk);
            }
        }

        // ---- polls (no barrier since C): waves0-3 z ; waves4-7 r ----
        if (tid < 256) {
            const u64* zb = zp + (size_t)(par * 32 + b) * 2048 + tid;
            u64 v0,v1,v2,v3,v4,v5,v6,v7; int tries = 0;
            for (;;) {
                v0 = agent_load64(zb);         v1 = agent_load64(zb + 256);
                v2 = agent_load64(zb + 512);   v3 = agent_load64(zb + 768);
                v4 = agent_load64(zb + 1024);  v5 = agent_load64(zb + 1280);
                v6 = agent_load64(zb + 1536);  v7 = agent_load64(zb + 1792);
                bool ok = ((unsigned)(v0 >> 32) > (unsigned)t) & ((unsigned)(v1 >> 32) > (unsigned)t)
                        & ((unsigned)(v2 >> 32) > (unsigned)t) & ((unsigned)(v3 >> 32) > (unsigned)t)
                        & ((unsigned)(v4 >> 32) > (unsigned)t) & ((unsigned)(v5 >> 32) > (unsigned)t)
                        & ((unsigned)(v6 >> 32) > (unsigned)t) & ((unsigned)(v7 >> 32) > (unsigned)t);
                if (__all(ok)) break;
                if (++tries > 2) __builtin_amdgcn_s_sleep(1);
            }
            float zs = __uint_as_float((unsigned)v0) + __uint_as_float((unsigned)v1)
                     + __uint_as_float((unsigned)v2) + __uint_as_float((unsigned)v3)
                     + __uint_as_float((unsigned)v4) + __uint_as_float((unsigned)v5)
                     + __uint_as_float((unsigned)v6) + __uint_as_float((unsigned)v7);
            float ee = __builtin_amdgcn_exp2f(zs);       // |zs| <= ~37, fp32-safe
            float sv = ee;
#pragma unroll
            for (int off = 32; off; off >>= 1) sv += __shfl_xor(sv, off, 64);
            if ((tid & 63) == 0) redb[par * 4 + (tid >> 6)] = sv;
            alb[par * 264 + tid] = ee;                   // e_t
        } else {
            const int t256 = tid - 256;
            if ((t256 >> 5) != j) {                      // own chunk already in LDS
                const u64* rp = &rch[(size_t)(par * 32 + b) * 256 + t256];
                u64 rv;
                for (;;) {
                    rv = agent_load64(rp);
                    if (__all((unsigned)(rv >> 32) >= (unsigned)t)) break;
                    __builtin_amdgcn_s_sleep(1);
                }
                rbb[par * 264 + t256] = __uint_as_float((unsigned)rv);   // r_{t-1}
            }
        }
        __syncthreads();
    }
}

extern "C" void kernel_launch(void* const* d_in, const int* in_sizes, int n_in,
                              void* d_out, int out_size, void* d_ws, size_t ws_size,
                              hipStream_t stream) {
    const float* x   = (const float*)d_in[0];
    const float* wy  = (const float*)d_in[1];
    const float* wh  = (const float*)d_in[2];
    const float* wr  = (const float*)d_in[3];
    const float* wal = (const float*)d_in[4];
    const float* wt  = (const float*)d_in[5];

    char* ws = (char*)d_ws;
    __half* wys    = (__half*)(ws + WYS_OFF);
    __half* prh    = (__half*)(ws + PR_OFF);
    __half* premh  = (__half*)(ws + PREMH_OFF);
    float*  hwh    = (float*)(ws + HWH_OFF);
    __half* wth    = (__half*)(ws + WTH_OFF);
    __half* wtrh   = (__half*)(ws + WTR_OFF);
    u64*    zp     = (u64*)(ws + ZP_OFF);
    u64*    rch    = (u64*)(ws + RCH_OFF);

    hipFuncSetAttribute((const void*)wbw_main,
                        hipFuncAttributeMaxDynamicSharedMemorySize, (int)LDS_TOTAL);

    // grid = 1568 GEMM blocks + 2112 cvt blocks (540672 quads / 256) = 3680
    prep_all<<<3680, 256, 0, stream>>>(x, wy, wh, wr, wt, wys, prh, hwh, wtrh, premh, wth);
    hipMemsetAsync(ws + ZP_OFF, 0, MEMSET_SZ, stream);

    wbw_main<<<256, 512, LDS_TOTAL, stream>>>(wys, prh, premh, wth, wtrh, hwh,
                                              wal, (float*)d_out, zp, rch);
}

// Round 13
// 448.241 us; speedup vs baseline: 1.0234x; 1.0234x over previous
//
#include <hip/hip_runtime.h>
#include <hip/hip_fp16.h>

typedef unsigned long long u64;

#define C2X 2.8853900817779268f   // 2*log2(e)
#define LOG2E 1.4426950408889634f

// ---------------- workspace layout (bytes) ----------------
#define WYS_OFF   0u          // half [32][256][256]  WY (prescaled C2X)
#define PR_OFF    4194304u    // half [32][256][256]  P_r = prem @ w_r
#define PREMH_OFF 8388608u    // half [32][256][256]  premise fp16
#define HWH_OFF   12582912u   // f32  [128][32][256]  (h@w_h)*C2X
#define WTH_OFF   16777216u   // half [256][256]      w_t
#define WTR_OFF   16908288u   // half [256][256]      W_tr = w_t @ w_r
#define ZP_OFF    17039360u   // u64 [2][32][8][256]  tagged z-partials (1MB)
#define RCH_OFF   18087936u   // u64 [2][32][256]     tagged r-chunks (128KB)
#define MEMSET_SZ 1179648u

// ---------------- LDS layout (bytes) ----------------
#define PRC_OFF    0u        // [256][32]h P_r
#define WTRC_OFF   16384u    // [256][32]h W_tr
#define PREMC_OFF  32768u    // [256][32]h prem
#define WTC_OFF    49152u    // [256][32]h w_t
#define WYC_OFF    65536u    // [256][32]h WY (prescaled)
#define HWHC_OFF   81920u    // [128][32] f32
#define SCH_OFF    98304u    // 32 f32
#define WACH_OFF   98432u    // 32 f32 (prescaled -2*LOG2E)
#define RED_OFF    98560u    // [2][4] f32 (+pad)
#define ALB_OFF    98624u    // [2][256] f32 e (unnormalized), parity dbuf
#define RBB_OFF    100672u   // 256 f32 r_{t-2}
#define PART_OFF   101696u   // [32][33] f32
#define LDS_TOTAL  105920u   // >80KB => 1 block/CU => all 256 co-resident

// ---------------- prep: everything in ONE launch (proven R7) ----------------
__global__ __launch_bounds__(256) void prep_all(const float* __restrict__ x,
                                                const float* __restrict__ wy,
                                                const float* __restrict__ wh,
                                                const float* __restrict__ wr,
                                                const float* __restrict__ wt,
                                                __half* __restrict__ wys,
                                                __half* __restrict__ prh,
                                                float* __restrict__ hwh,
                                                __half* __restrict__ wtrh,
                                                __half* __restrict__ premh,
                                                __half* __restrict__ wth) {
    const int blk = blockIdx.x;
    if (blk >= 1568) {
        int i = (blk - 1568) * 256 + threadIdx.x;   // quad index
        float4 v; __half* dst; int e;
        if (i < 524288) {
            e = i * 4; int b = e >> 16;
            v = *(const float4*)(x + (size_t)e + (size_t)b * 32768);
            dst = premh + e;
        } else if (i < 540672) {
            e = (i - 524288) * 4;
            v = *(const float4*)(wt + e);
            dst = wth + e;
        } else return;
        __half h[4] = {__float2half(v.x),__float2half(v.y),__float2half(v.z),__float2half(v.w)};
        *(uint2*)dst = *(const uint2*)h;
        return;
    }
    __shared__ float At[8][256];
    const int d = threadIdx.x;
    int mode, row0;
    if (blk < 1024)      { mode = 0; row0 = blk * 8; }
    else if (blk < 1536) { mode = 1; row0 = (blk - 1024) * 8; }
    else                 { mode = 2; row0 = (blk - 1536) * 8; }
    for (int rr = 0; rr < 8; ++rr) {
        int r = row0 + rr;
        const float* src;
        if (mode == 0)      { int b = r >> 8, l = r & 255; src = x + (size_t)(b * 384 + l) * 256; }
        else if (mode == 1) { int tt = r >> 5, bb = r & 31; src = x + (size_t)(bb * 384 + 256 + tt) * 256; }
        else                { src = wt + (size_t)r * 256; }
        At[rr][d] = src[d];
    }
    __syncthreads();
    if (mode == 0) {
        float accy[8] = {0,0,0,0,0,0,0,0}, accr[8] = {0,0,0,0,0,0,0,0};
        for (int k = 0; k < 256; k += 2) {
            float y0 = wy[(size_t)k * 256 + d], y1 = wy[(size_t)(k + 1) * 256 + d];
            float r0 = wr[(size_t)k * 256 + d], r1 = wr[(size_t)(k + 1) * 256 + d];
#pragma unroll
            for (int rr = 0; rr < 8; ++rr) {
                float2 a = *(const float2*)&At[rr][k];
                accy[rr] = fmaf(a.x, y0, accy[rr]); accy[rr] = fmaf(a.y, y1, accy[rr]);
                accr[rr] = fmaf(a.x, r0, accr[rr]); accr[rr] = fmaf(a.y, r1, accr[rr]);
            }
        }
        for (int rr = 0; rr < 8; ++rr) {
            int r = row0 + rr;
            wys[(size_t)r * 256 + d] = __float2half(accy[rr] * C2X);
            prh[(size_t)r * 256 + d] = __float2half(accr[rr]);
        }
    } else {
        const float* w = (mode == 1) ? wh : wr;
        float acc[8] = {0,0,0,0,0,0,0,0};
        for (int k = 0; k < 256; k += 4) {
            float w0 = w[(size_t)k * 256 + d], w1 = w[(size_t)(k+1) * 256 + d];
            float w2 = w[(size_t)(k+2) * 256 + d], w3 = w[(size_t)(k+3) * 256 + d];
#pragma unroll
            for (int rr = 0; rr < 8; ++rr) {
                float4 a = *(const float4*)&At[rr][k];
                float t0 = fmaf(a.x, w0, acc[rr]);
                t0 = fmaf(a.y, w1, t0);
                t0 = fmaf(a.z, w2, t0);
                acc[rr] = fmaf(a.w, w3, t0);
            }
        }
        for (int rr = 0; rr < 8; ++rr) {
            int r = row0 + rr;
            if (mode == 1) hwh[(size_t)r * 256 + d] = acc[rr] * C2X;
            else           wtrh[(size_t)r * 256 + d] = __float2half(acc[rr]);
        }
    }
}

// ---------------- agent-scope helpers ----------------
__device__ __forceinline__ u64 agent_load64(const u64* p) {
    return __hip_atomic_load(p, __ATOMIC_RELAXED, __HIP_MEMORY_SCOPE_AGENT);
}
__device__ __forceinline__ void agent_store64(u64* p, u64 v) {
    __hip_atomic_store(p, v, __ATOMIC_RELAXED, __HIP_MEMORY_SCOPE_AGENT);
}

// ---------------- main: R7 skeleton + split-poll E, LDS self-shortcut (R11 best) ----------------
__global__ __launch_bounds__(512, 1) void wbw_main(
    const __half* __restrict__ wys, const __half* __restrict__ prh,
    const __half* __restrict__ premh, const __half* __restrict__ wth,
    const __half* __restrict__ wtrh, const float* __restrict__ hwh,
    const float* __restrict__ walpha, float* __restrict__ out,
    u64* __restrict__ zp, u64* __restrict__ rch)
{
    extern __shared__ char lds[];
    const int tid = threadIdx.x;
    const int b = blockIdx.x >> 3, j = blockIdx.x & 7;

    float* hwhc  = (float*)(lds + HWHC_OFF);
    float* s_ch  = (float*)(lds + SCH_OFF);
    float* wa_ch = (float*)(lds + WACH_OFF);
    float* redb  = (float*)(lds + RED_OFF);
    float* alb   = (float*)(lds + ALB_OFF);    // [2][256] e, parity dbuf
    float* rbb   = (float*)(lds + RBB_OFF);    // r_{t-2}
    float* part  = (float*)(lds + PART_OFF);   // [32][33]

    // ---- stage the five [256][32] fp16 column-chunk matrices ----
    {
        const int prt = tid & 3;
        for (int it = 0; it < 2; ++it) {
            int row = it * 128 + (tid >> 2);
            size_t g = (size_t)row * 256 + j * 32 + prt * 8;
            unsigned lo = (unsigned)row * 64 + (unsigned)prt * 16;
            *(uint4*)(lds + PRC_OFF   + lo) = *(const uint4*)(prh   + (size_t)b * 65536 + g);
            *(uint4*)(lds + WTRC_OFF  + lo) = *(const uint4*)(wtrh  + g);
            *(uint4*)(lds + PREMC_OFF + lo) = *(const uint4*)(premh + (size_t)b * 65536 + g);
            *(uint4*)(lds + WTC_OFF   + lo) = *(const uint4*)(wth   + g);
            *(uint4*)(lds + WYC_OFF   + lo) = *(const uint4*)(wys   + (size_t)b * 65536 + g);
        }
    }
    for (int it = 0; it < 8; ++it) {
        int idx = it * 512 + tid;
        int tt = idx >> 5, dd = idx & 31;
        hwhc[idx] = hwh[((size_t)tt * 32 + b) * 256 + j * 32 + dd];
    }
    if (tid < 32)  wa_ch[tid] = walpha[j * 32 + tid] * (-2.0f * LOG2E);
    if (tid < 256) { alb[tid] = 0.f; alb[256 + tid] = 0.f; rbb[tid] = 0.f; }
    if (tid < 8)   redb[tid] = (tid == 0 || tid == 4) ? 1.f : 0.f;
    __syncthreads();

    for (int t = 0; t <= 128; ++t) {
        const int par = t & 1, q = par ^ 1;
        const float* e1 = alb + q * 256;           // e_{t-1} (raw, unnormalized)
        if (t < 128) {
            // ---- P1: s-partials. waves0-3: e@P_r ; waves4-7: rbb@W_tr ----
            {
                const int half_ = tid >> 8;
                const int s16 = (tid >> 4) & 15;
                const int d0 = (tid & 15) * 2;
                const __half* mat = (const __half*)(lds + (half_ ? WTRC_OFF : PRC_OFF));
                const float* vec = half_ ? rbb : e1;
                float ax = 0.f, ay = 0.f;
#pragma unroll
                for (int i = 0; i < 16; ++i) {
                    int l = s16 + i * 16;
                    float v = vec[l];
                    float2 mf = __half22float2(*(const __half2*)&mat[l * 32 + d0]);
                    ax = fmaf(v, mf.x, ax); ay = fmaf(v, mf.y, ay);
                }
                const int row = half_ * 16 + s16;
                part[row * 33 + d0] = ax; part[row * 33 + d0 + 1] = ay;
            }
            __syncthreads();
            // ---- B: s_ch = hwh + C2X*(se*rD + sr)  (64 threads, halved depth) ----
            if (tid < 64) {
                const int d = tid & 31, h = tid >> 5;
                float sum = 0.f;
#pragma unroll
                for (int s = 0; s < 16; ++s) sum += part[(h * 16 + s) * 33 + d];
                float other = __shfl_xor(sum, 32, 64);
                if (h == 0) {
                    const float* rd = redb + q * 4;
                    float rD = __builtin_amdgcn_rcpf(rd[0] + rd[1] + rd[2] + rd[3]);
                    float sv = fmaf(sum, rD, other);
                    s_ch[d] = fmaf(sv, C2X, hwhc[t * 32 + d]);
                }
            }
            __syncthreads();
            // ---- C: sigma + tagged z publish (all 512 threads) ----
            {
                const int l = tid >> 1, dh = (tid & 1) << 4;
                union { uint4 u[2]; __half h[16]; } W;
                W.u[0] = *(const uint4*)(lds + WYC_OFF + (unsigned)l * 64 + (unsigned)dh * 2);
                W.u[1] = *(const uint4*)(lds + WYC_OFF + (unsigned)l * 64 + (unsigned)dh * 2 + 16);
                float acc = 0.f;
#pragma unroll
                for (int i = 0; i < 16; ++i) {
                    float arg = __half2float(W.h[i]) + s_ch[dh + i];
                    acc = fmaf(wa_ch[dh + i],
                               __builtin_amdgcn_rcpf(__builtin_amdgcn_exp2f(arg) + 1.f), acc);
                }
                acc += __shfl_xor(acc, 1, 64);
                if ((tid & 1) == 0) {
                    u64 pk = ((u64)(unsigned)(t + 1) << 32) | (u64)__float_as_uint(acc);
                    agent_store64(&zp[(size_t)((par * 32 + b) * 8 + j) * 256 + l], pk);
                }
            }
        }
        // ---- D (after publish, off z-chain): r-partials. e@prem | rbb@w_t ----
        {
            const int half_ = tid >> 8;
            const int s16 = (tid >> 4) & 15;
            const int d0 = (tid & 15) * 2;
            const __half* mat = (const __half*)(lds + (half_ ? WTC_OFF : PREMC_OFF));
            const float* vec = half_ ? rbb : e1;   // raw e; rD applied in reduce
            float ax = 0.f, ay = 0.f;
#pragma unroll
            for (int i = 0; i < 16; ++i) {
                int l = s16 + i * 16;
                float v = vec[l];
                float2 mf = __half22float2(*(const __half2*)&mat[l * 32 + d0]);
                ax = fmaf(v, mf.x, ax); ay = fmaf(v, mf.y, ay);
            }
            const int row = half_ * 16 + s16;
            part[row * 33 + d0] = ax; part[row * 33 + d0 + 1] = ay;
        }
        __syncthreads();
        // ---- E: wave4 r-reduce+out+publish+LDS; waves4-7 r-poll ∥ waves0-3 z-poll ----
        if (tid >= 256) {
            const int t256 = tid - 256;
            if (t256 < 64) {                       // wave 4: finalize r_{t-1}
                const int d = t256 & 31, h = t256 >> 5;
                float sum = 0.f;
#pragma unroll
                for (int s = 0; s < 16; ++s) sum += part[(h * 16 + s) * 33 + d];
                float other = __shfl_xor(sum, 32, 64);
                if (h == 0) {
                    const float* rd = redb + q * 4;
                    float rD = __builtin_amdgcn_rcpf(rd[0] + rd[1] + rd[2] + rd[3]);
                    float rv = fmaf(sum, rD, other);
                    if (t >= 1) out[((size_t)b * 128 + (t - 1)) * 256 + j * 32 + d] = rv;
                    rbb[j * 32 + d] = rv;          // LDS shortcut for own chunk
                    if (t < 128) {
                        u64 pk = ((u64)(unsigned)t << 32) | (u64)__float_as_uint(rv);
                        agent_store64(&rch[(size_t)(par * 32 + b) * 256 + j * 32 + d], pk);
                    }
                }
            }
            // r-poll (tag >= t), one entry per thread; skip own chunk (LDS-fresh)
            if (t < 128 && (t256 >> 5) != j) {
                const u64* rp = &rch[(size_t)(par * 32 + b) * 256 + t256];
                u64 rv;
                for (;;) {
                    rv = agent_load64(rp);
                    if (__all((unsigned)(rv >> 32) >= (unsigned)t)) break;
                    __builtin_amdgcn_s_sleep(1);
                }
                rbb[t256] = __uint_as_float((unsigned)rv);   // r_{t-1}
            }
        } else if (t < 128) {
            // z-poll (tag > t) + exp + denom partials + e_t
            const u64* zb = zp + (size_t)(par * 32 + b) * 2048 + tid;
            u64 v0,v1,v2,v3,v4,v5,v6,v7; int tries = 0;
            for (;;) {
                v0 = agent_load64(zb);         v1 = agent_load64(zb + 256);
                v2 = agent_load64(zb + 512);   v3 = agent_load64(zb + 768);
                v4 = agent_load64(zb + 1024);  v5 = agent_load64(zb + 1280);
                v6 = agent_load64(zb + 1536);  v7 = agent_load64(zb + 1792);
                bool ok = ((unsigned)(v0 >> 32) > (unsigned)t) & ((unsigned)(v1 >> 32) > (unsigned)t)
                        & ((unsigned)(v2 >> 32) > (unsigned)t) & ((unsigned)(v3 >> 32) > (unsigned)t)
                        & ((unsigned)(v4 >> 32) > (unsigned)t) & ((unsigned)(v5 >> 32) > (unsigned)t)
                        & ((unsigned)(v6 >> 32) > (unsigned)t) & ((unsigned)(v7 >> 32) > (unsigned)t);
                if (__all(ok)) break;
                if (++tries > 2) __builtin_amdgcn_s_sleep(1);
            }
            float zs = __uint_as_float((unsigned)v0) + __uint_as_float((unsigned)v1)
                     + __uint_as_float((unsigned)v2) + __uint_as_float((unsigned)v3)
                     + __uint_as_float((unsigned)v4) + __uint_as_float((unsigned)v5)
                     + __uint_as_float((unsigned)v6) + __uint_as_float((unsigned)v7);
            float ee = __builtin_amdgcn_exp2f(zs);       // |zs| <= ~37, fp32-safe
            float sv = ee;
#pragma unroll
            for (int off = 32; off; off >>= 1) sv += __shfl_xor(sv, off, 64);
            if ((tid & 63) == 0) redb[par * 4 + (tid >> 6)] = sv;
            alb[par * 256 + tid] = ee;                   // e_t
        }
        __syncthreads();
    }
}

extern "C" void kernel_launch(void* const* d_in, const int* in_sizes, int n_in,
                              void* d_out, int out_size, void* d_ws, size_t ws_size,
                              hipStream_t stream) {
    const float* x   = (const float*)d_in[0];
    const float* wy  = (const float*)d_in[1];
    const float* wh  = (const float*)d_in[2];
    const float* wr  = (const float*)d_in[3];
    const float* wal = (const float*)d_in[4];
    const float* wt  = (const float*)d_in[5];

    char* ws = (char*)d_ws;
    __half* wys    = (__half*)(ws + WYS_OFF);
    __half* prh    = (__half*)(ws + PR_OFF);
    __half* premh  = (__half*)(ws + PREMH_OFF);
    float*  hwh    = (float*)(ws + HWH_OFF);
    __half* wth    = (__half*)(ws + WTH_OFF);
    __half* wtrh   = (__half*)(ws + WTR_OFF);
    u64*    zp     = (u64*)(ws + ZP_OFF);
    u64*    rch    = (u64*)(ws + RCH_OFF);

    hipFuncSetAttribute((const void*)wbw_main,
                        hipFuncAttributeMaxDynamicSharedMemorySize, (int)LDS_TOTAL);

    // grid = 1568 GEMM blocks + 2112 cvt blocks (540672 quads / 256) = 3680
    prep_all<<<3680, 256, 0, stream>>>(x, wy, wh, wr, wt, wys, prh, hwh, wtrh, premh, wth);
    hipMemsetAsync(ws + ZP_OFF, 0, MEMSET_SZ, stream);

    wbw_main<<<256, 512, LDS_TOTAL, stream>>>(wys, prh, premh, wth, wtrh, hwh,
                                              wal, (float*)d_out, zp, rch);
}